// Round 1
// baseline (11842.133 us; speedup 1.0000x reference)
//
#include <hip/hip_runtime.h>
#include <math.h>

#define B_  64
#define S_  512
#define I_  512
#define H_  512
#define G4  2048   // 4*H

// ---------------- workspace layout ----------------
// [0]      Ut   : [G4][512] fp32 (4 MB)  concat-U transposed: Ut[col4][k]
// [4MB]    Wt   : [G4][512] fp32 (4 MB)  concat-W transposed (fused fallback)
// [8MB]    bcat : [G4] fp32 (pad to 64KB)
// then     h0, h1, c : [B][H] fp32 (128 KB each)
// [16MB]   xw   : [S][B][G4] fp32 (256 MB)   (pre-path only)
static const size_t OFF_UT = 0;
static const size_t OFF_WT = (size_t)G4 * 512 * 4;
static const size_t OFF_B  = OFF_WT + (size_t)G4 * 512 * 4;
static const size_t OFF_H0 = OFF_B + 64 * 1024;
static const size_t OFF_H1 = OFF_H0 + (size_t)B_ * H_ * 4;
static const size_t OFF_C  = OFF_H1 + (size_t)B_ * H_ * 4;
static const size_t OFF_XW = 16ull * 1024 * 1024;
static const size_t PRE_BYTES = OFF_XW + (size_t)S_ * B_ * G4 * 4;  // ~272 MB

// 32x32 LDS tile transpose: dst[c][k] = src[k][c], both 512x512
__global__ __launch_bounds__(256) void transpose512(const float* __restrict__ src,
                                                    float* __restrict__ dst) {
    __shared__ float t[32][33];
    int k0 = blockIdx.x * 32;
    int c0 = blockIdx.y * 32;
    int tx = threadIdx.x & 31, ty = threadIdx.x >> 5;  // 32 x 8
    #pragma unroll
    for (int i = 0; i < 32; i += 8)
        t[ty + i][tx] = src[(size_t)(k0 + ty + i) * 512 + c0 + tx];
    __syncthreads();
    #pragma unroll
    for (int i = 0; i < 32; i += 8)
        dst[(size_t)(c0 + ty + i) * 512 + k0 + tx] = t[tx][ty + i];
}

__global__ __launch_bounds__(256) void pack_bias(const float* __restrict__ bf,
                                                 const float* __restrict__ bi,
                                                 const float* __restrict__ bo,
                                                 const float* __restrict__ bc,
                                                 float* __restrict__ bcat) {
    int i = blockIdx.x * 256 + threadIdx.x;  // 2048
    const float* p = (i < 512) ? bf : (i < 1024) ? bi : (i < 1536) ? bo : bc;
    bcat[i] = p[i & 511];
}

__global__ __launch_bounds__(256) void zero_hc(float* __restrict__ h0, float* __restrict__ c) {
    int i = blockIdx.x * 256 + threadIdx.x;  // B*H = 32768
    h0[i] = 0.f;
    c[i] = 0.f;
}

// xw[(s*64+b)*2048 + col] = x[row=b*512+s][:] . Wg[:][col] + bcat[col]
// Tiles: BM=128 (rows of M=B*S), BN=64, BK=16. 256 thr, 8x4 microtile.
__global__ __launch_bounds__(256) void proj_gemm(
    const float* __restrict__ x,
    const float* __restrict__ Wf, const float* __restrict__ Wi,
    const float* __restrict__ Wo, const float* __restrict__ Wc,
    const float* __restrict__ bcat, float* __restrict__ xw) {
    __shared__ float As[16][136];  // [k][m], padded to break store conflicts
    __shared__ float Bs[16][64];
    int m0 = blockIdx.x * 128;
    int n0 = blockIdx.y * 64;
    int gate = n0 >> 9;
    const float* Wg = (gate == 0) ? Wf : (gate == 1) ? Wi : (gate == 2) ? Wo : Wc;
    int cg0 = n0 & 511;
    int tid = threadIdx.x;
    int tm = tid >> 4, tn = tid & 15;
    float acc[8][4] = {};
    for (int kt = 0; kt < 512; kt += 16) {
        {   // A tile: 128 rows x 16 k ; x is [row][512] with row=b*512+s
            int r = tid >> 2, kq = (tid & 3) * 4;
            #pragma unroll
            for (int p = 0; p < 2; ++p) {
                int row = m0 + r + p * 64;
                float4 v = *(const float4*)&x[(size_t)row * I_ + kt + kq];
                As[kq + 0][r + p * 64] = v.x;
                As[kq + 1][r + p * 64] = v.y;
                As[kq + 2][r + p * 64] = v.z;
                As[kq + 3][r + p * 64] = v.w;
            }
            // B tile: 16 k x 64 cols
            int kr = tid >> 4, cl = (tid & 15) * 4;
            *(float4*)&Bs[kr][cl] = *(const float4*)&Wg[(size_t)(kt + kr) * 512 + cg0 + cl];
        }
        __syncthreads();
        #pragma unroll
        for (int k = 0; k < 16; ++k) {
            float a[8], b[4];
            *(float4*)&a[0] = *(float4*)&As[k][tm * 8];
            *(float4*)&a[4] = *(float4*)&As[k][tm * 8 + 4];
            *(float4*)&b[0] = *(float4*)&Bs[k][tn * 4];
            #pragma unroll
            for (int i2 = 0; i2 < 8; ++i2)
                #pragma unroll
                for (int j = 0; j < 4; ++j) acc[i2][j] += a[i2] * b[j];
        }
        __syncthreads();
    }
    #pragma unroll
    for (int i2 = 0; i2 < 8; ++i2) {
        int row = m0 + tm * 8 + i2;
        int b = row >> 9, s = row & 511;
        int col = n0 + tn * 4;
        float4 v;
        v.x = acc[i2][0] + bcat[col + 0];
        v.y = acc[i2][1] + bcat[col + 1];
        v.z = acc[i2][2] + bcat[col + 2];
        v.w = acc[i2][3] + bcat[col + 3];
        *(float4*)&xw[((size_t)s * 64 + b) * G4 + col] = v;
    }
}

// One timestep. Grid (64 col-blocks, 4 batch-blocks), 256 threads.
// Block: 16 batch rows x 8 hidden cols x 4 gates (32 U-cols).
// PRE:   g = xw_t[b][col4] + h . Ut[col4][:]
// FUSED: g = bcat[col4] + h . Ut[col4][:] + x_t . Wt[col4][:]
template <bool FUSED>
__global__ __launch_bounds__(256) void lstm_step(
    const float* __restrict__ xw_t,  // [B][G4] slice for this s (PRE)
    const float* __restrict__ x,     // full x (FUSED)
    const float* __restrict__ Ut,    // [G4][512]
    const float* __restrict__ Wt,    // [G4][512] (FUSED)
    const float* __restrict__ bcat,  // [G4]
    const float* __restrict__ h_in,  // [B][H]
    float* __restrict__ h_out,       // [B][H]
    float* __restrict__ c_st,        // [B][H] in/out (in-place per-element)
    float* __restrict__ out,         // d_out: result [B][S][H]
    int s) {
    __shared__ float hs[16][512];   // h rows (reused for x rows in FUSED pass 2)
    __shared__ float Us[32][68];    // staged U/W col-slices, padded
    __shared__ float gs[16][32];
    int cb = blockIdx.x;          // 0..63 -> 8 hidden cols
    int bb = blockIdx.y;          // 0..3  -> 16 batch rows
    int hc0 = cb * 8;
    int b0 = bb * 16;
    int tid = threadIdx.x;
    int col_l = tid & 31;         // gate*8 + c
    int g = col_l >> 3, c = col_l & 7;
    int col4 = g * 512 + hc0 + c;
    int r0 = tid >> 5;            // 0..7 ; rows r0 and r0+8

    // stage h rows (contiguous 16*512 floats)
    {
        const float4* src = (const float4*)&h_in[(size_t)b0 * 512];
        float4* dst = (float4*)&hs[0][0];
        #pragma unroll
        for (int i = 0; i < 8; ++i) dst[tid + i * 256] = src[tid + i * 256];
    }

    float acc0, acc1;
    if (FUSED) {
        acc0 = bcat[col4];
        acc1 = acc0;
    } else {
        acc0 = xw_t[(size_t)(b0 + r0) * G4 + col4];
        acc1 = xw_t[(size_t)(b0 + r0 + 8) * G4 + col4];
    }
    __syncthreads();

    // ---- pass over recurrent weights ----
    for (int kt = 0; kt < 512; kt += 64) {
        int col_s = tid >> 3, kh = tid & 7;
        const float* up = Ut + (size_t)((col_s >> 3) * 512 + hc0 + (col_s & 7)) * 512 + kt + kh * 8;
        *(float4*)&Us[col_s][kh * 8]     = *(const float4*)&up[0];
        *(float4*)&Us[col_s][kh * 8 + 4] = *(const float4*)&up[4];
        __syncthreads();
        #pragma unroll
        for (int kk = 0; kk < 64; kk += 4) {
            float4 u  = *(float4*)&Us[col_l][kk];
            float4 ha = *(float4*)&hs[r0][kt + kk];
            float4 hb = *(float4*)&hs[r0 + 8][kt + kk];
            acc0 += u.x * ha.x + u.y * ha.y + u.z * ha.z + u.w * ha.w;
            acc1 += u.x * hb.x + u.y * hb.y + u.z * hb.z + u.w * hb.w;
        }
        __syncthreads();
    }

    if (FUSED) {
        // restage hs with x rows: x[(b0+r)*512 + s][k]
        __syncthreads();
        for (int i = tid; i < 16 * 128; i += 256) {
            int r = i >> 7, kq = i & 127;
            ((float4*)&hs[r][0])[kq] =
                ((const float4*)&x[((size_t)(b0 + r) * 512 + s) * 512])[kq];
        }
        __syncthreads();
        for (int kt = 0; kt < 512; kt += 64) {
            int col_s = tid >> 3, kh = tid & 7;
            const float* wp = Wt + (size_t)((col_s >> 3) * 512 + hc0 + (col_s & 7)) * 512 + kt + kh * 8;
            *(float4*)&Us[col_s][kh * 8]     = *(const float4*)&wp[0];
            *(float4*)&Us[col_s][kh * 8 + 4] = *(const float4*)&wp[4];
            __syncthreads();
            #pragma unroll
            for (int kk = 0; kk < 64; kk += 4) {
                float4 u  = *(float4*)&Us[col_l][kk];
                float4 ha = *(float4*)&hs[r0][kt + kk];
                float4 hb = *(float4*)&hs[r0 + 8][kt + kk];
                acc0 += u.x * ha.x + u.y * ha.y + u.z * ha.z + u.w * ha.w;
                acc1 += u.x * hb.x + u.y * hb.y + u.z * hb.z + u.w * hb.w;
            }
            __syncthreads();
        }
    }

    // ---- gate epilogue ----
    gs[r0][col_l] = acc0;
    gs[r0 + 8][col_l] = acc1;
    __syncthreads();
    if (tid < 128) {
        int r = tid >> 3, cc2 = tid & 7;
        float gf = gs[r][cc2];
        float gi = gs[r][8 + cc2];
        float go = gs[r][16 + cc2];
        float gc = gs[r][24 + cc2];
        float f_ = 1.f / (1.f + expf(-gf));
        float i_ = 1.f / (1.f + expf(-gi));
        float o_ = 1.f / (1.f + expf(-go));
        float ch = tanhf(gc);
        int b = b0 + r, hc = hc0 + cc2;
        size_t idx = (size_t)b * 512 + hc;
        float cn = f_ * c_st[idx] + i_ * ch;
        float hn = o_ * tanhf(cn);
        c_st[idx] = cn;
        h_out[idx] = hn;
        out[((size_t)b * S_ + s) * H_ + hc] = hn;
    }
}

__global__ __launch_bounds__(256) void copy_hc(const float* __restrict__ hT,
                                               const float* __restrict__ cT,
                                               float* __restrict__ out) {
    int i = blockIdx.x * 256 + threadIdx.x;  // 32768
    out[(size_t)B_ * S_ * H_ + i] = hT[i];
    out[(size_t)B_ * S_ * H_ + B_ * H_ + i] = cT[i];
}

extern "C" void kernel_launch(void* const* d_in, const int* in_sizes, int n_in,
                              void* d_out, int out_size, void* d_ws, size_t ws_size,
                              hipStream_t stream) {
    const float* x  = (const float*)d_in[0];
    const float* Wf = (const float*)d_in[1];
    const float* Uf = (const float*)d_in[2];
    const float* bf = (const float*)d_in[3];
    const float* Wi = (const float*)d_in[4];
    const float* Ui = (const float*)d_in[5];
    const float* bi = (const float*)d_in[6];
    const float* Wo = (const float*)d_in[7];
    const float* Uo = (const float*)d_in[8];
    const float* bo = (const float*)d_in[9];
    const float* Wc = (const float*)d_in[10];
    const float* Uc = (const float*)d_in[11];
    const float* bc = (const float*)d_in[12];
    float* out = (float*)d_out;
    char* ws = (char*)d_ws;
    float* Ut   = (float*)(ws + OFF_UT);
    float* Wt   = (float*)(ws + OFF_WT);
    float* bcat = (float*)(ws + OFF_B);
    float* h0   = (float*)(ws + OFF_H0);
    float* h1   = (float*)(ws + OFF_H1);
    float* cbuf = (float*)(ws + OFF_C);
    float* xw   = (float*)(ws + OFF_XW);
    const bool pre = (ws_size >= PRE_BYTES);

    dim3 tb(256);
    dim3 tg(16, 16);
    // one-time (per launch) weight repacks — identical work every call
    transpose512<<<tg, tb, 0, stream>>>(Uf, Ut + 0 * 512 * 512);
    transpose512<<<tg, tb, 0, stream>>>(Ui, Ut + 1 * 512 * 512);
    transpose512<<<tg, tb, 0, stream>>>(Uo, Ut + 2 * 512 * 512);
    transpose512<<<tg, tb, 0, stream>>>(Uc, Ut + 3 * 512 * 512);
    transpose512<<<tg, tb, 0, stream>>>(Wf, Wt + 0 * 512 * 512);
    transpose512<<<tg, tb, 0, stream>>>(Wi, Wt + 1 * 512 * 512);
    transpose512<<<tg, tb, 0, stream>>>(Wo, Wt + 2 * 512 * 512);
    transpose512<<<tg, tb, 0, stream>>>(Wc, Wt + 3 * 512 * 512);
    pack_bias<<<8, tb, 0, stream>>>(bf, bi, bo, bc, bcat);
    zero_hc<<<128, tb, 0, stream>>>(h0, cbuf);

    if (pre)
        proj_gemm<<<dim3(256, 32), tb, 0, stream>>>(x, Wf, Wi, Wo, Wc, bcat, xw);

    for (int s = 0; s < S_; ++s) {
        float* hin  = (s & 1) ? h1 : h0;
        float* hout = (s & 1) ? h0 : h1;
        if (pre)
            lstm_step<false><<<dim3(64, 4), tb, 0, stream>>>(
                xw + (size_t)s * B_ * G4, nullptr, Ut, nullptr, bcat,
                hin, hout, cbuf, out, s);
        else
            lstm_step<true><<<dim3(64, 4), tb, 0, stream>>>(
                nullptr, x, Ut, Wt, bcat, hin, hout, cbuf, out, s);
    }
    // s=511 wrote hout = h0 ; c is in cbuf
    copy_hc<<<128, tb, 0, stream>>>(h0, cbuf, out);
}